// Round 1
// baseline (1183.479 us; speedup 1.0000x reference)
//
#include <hip/hip_runtime.h>

// InteractionArch: per-sample Gram matrix of 27x128 fp32, strict upper triangle out.
// B=65536, F=27 (1 dense + 26 sparse), D=128, out 351 fp32/sample.

constexpr int F      = 27;
constexpr int NPAIRS = F * (F - 1) / 2;   // 351
constexpr int D      = 128;
constexpr int DC     = 32;                // d-chunk staged in LDS
constexpr int NQ     = DC / 4;            // float4 per row-chunk = 8
constexpr int SPB    = 8;                 // samples per block
constexpr int RP     = 36;                // padded LDS row stride (floats), 16B-aligned
constexpr int LPS    = F * RP;            // 972 floats per sample
constexpr int NT     = 7;                 // row classes: i mod 7 (strided tiles of 4 rows)
constexpr int NTP    = NT * (NT + 1) / 2; // 28 class-pairs per sample

__global__ __launch_bounds__(256)
void interact_kernel(const float* __restrict__ dense,
                     const float* __restrict__ sparse,
                     float* __restrict__ out, int B) {
    __shared__ float lds[SPB * LPS];   // 31104 B

    const int tid = threadIdx.x;
    const int s   = tid >> 5;          // sample slot in block: 0..7
    const int p   = tid & 31;          // class-pair slot: 0..31 (28 active)
    const long b  = (long)blockIdx.x * SPB + s;

    // decode class-pair p -> (ti, tj), ti <= tj, row-major over upper triangle incl diag
    int ti = 0, rem = p;
    while (ti < NT - 1 && rem >= NT - ti) { rem -= NT - ti; ++ti; }
    int tj = ti + rem;                 // p>=28 gives tj>=NT; harmless (reads clamped, no stores)

    float acc[4][4];
    #pragma unroll
    for (int a = 0; a < 4; ++a)
        #pragma unroll
        for (int c = 0; c < 4; ++c) acc[a][c] = 0.0f;

    const int nload = SPB * F * NQ;    // 1728 float4 loads per chunk per block

    for (int c = 0; c < D / DC; ++c) {
        __syncthreads();               // previous compute done before overwrite
        // ---- stage chunk: 8 samples x 27 rows x 32 floats, coalesced float4 ----
        for (int idx = tid; idx < nload; idx += 256) {
            int q  = idx & (NQ - 1);       // float4 slot within row-chunk
            int t  = idx >> 3;             // 0..215
            int ls = t / F;                // sample slot
            int n  = t - ls * F;           // feature row 0..26
            long bb = (long)blockIdx.x * SPB + ls;
            if (bb < B) {
                const float* src = (n == 0)
                    ? dense  + bb * (long)D + c * DC + q * 4
                    : sparse + ((bb * 26) + (n - 1)) * (long)D + c * DC + q * 4;
                float4 v = *(const float4*)src;
                *(float4*)&lds[(ls * F + n) * RP + q * 4] = v;
            }
        }
        __syncthreads();
        // ---- accumulate 4x4 strided tile: rows ti+7a vs tj+7b ----
        const float* base = &lds[s * LPS];
        #pragma unroll
        for (int dq = 0; dq < DC; dq += 4) {
            float4 av[4], bv[4];
            #pragma unroll
            for (int a = 0; a < 4; ++a) {
                int ri = ti + 7 * a; ri = ri < F ? ri : F - 1;
                int rj = tj + 7 * a; rj = rj < F ? rj : F - 1;
                av[a] = *(const float4*)&base[ri * RP + dq];
                bv[a] = *(const float4*)&base[rj * RP + dq];
            }
            #pragma unroll
            for (int a = 0; a < 4; ++a)
                #pragma unroll
                for (int bq = 0; bq < 4; ++bq) {
                    acc[a][bq] = fmaf(av[a].x, bv[bq].x, acc[a][bq]);
                    acc[a][bq] = fmaf(av[a].y, bv[bq].y, acc[a][bq]);
                    acc[a][bq] = fmaf(av[a].z, bv[bq].z, acc[a][bq]);
                    acc[a][bq] = fmaf(av[a].w, bv[bq].w, acc[a][bq]);
                }
        }
    }

    // ---- epilogue: scatter valid pairs to triu-packed output ----
    if (p < NTP && b < B) {
        float* ob = out + b * (long)NPAIRS;
        #pragma unroll
        for (int a = 0; a < 4; ++a) {
            int ri = ti + 7 * a;
            if (ri >= F) continue;
            #pragma unroll
            for (int bq = 0; bq < 4; ++bq) {
                int rj = tj + 7 * bq;
                if (rj >= F) continue;
                if (ti == tj) {            // diagonal class: pair appears as (a,bq) and (bq,a)
                    if (a >= bq) continue; // keep a<bq; also drops ri==rj
                }
                int i = ri < rj ? ri : rj;
                int j = ri < rj ? rj : ri;
                int o = i * (2 * F - i - 1) / 2 + (j - i - 1);
                ob[o] = acc[a][bq];
            }
        }
    }
}

extern "C" void kernel_launch(void* const* d_in, const int* in_sizes, int n_in,
                              void* d_out, int out_size, void* d_ws, size_t ws_size,
                              hipStream_t stream) {
    const float* dense  = (const float*)d_in[0];
    const float* sparse = (const float*)d_in[1];
    float* out = (float*)d_out;
    const int B = in_sizes[0] / D;                 // 65536
    const int grid = (B + SPB - 1) / SPB;          // 8192
    interact_kernel<<<grid, 256, 0, stream>>>(dense, sparse, out, B);
}